// Round 10
// baseline (399.813 us; speedup 1.0000x reference)
//
#include <hip/hip_runtime.h>
#include <hip/hip_bf16.h>
#include <math.h>

// Problem constants
#define Bn 2
#define Tn 2048
#define En 1024
#define Hn 16
#define DFFn 4096
#define Mn (Bn*Tn)   // 4096 rows
#define QKVLD 3072   // fused QKV leading dim

typedef __hip_bfloat16 bf16;
typedef unsigned short u16;
typedef unsigned int u32;
typedef __attribute__((ext_vector_type(8))) short short8;
typedef __attribute__((ext_vector_type(4))) float f32x4;

typedef __attribute__((address_space(1))) const void cg_void;
typedef __attribute__((address_space(3))) void lds_void;

// Q pre-scale folded into QKV GEMM: E^-0.5 * log2(e)
#define QSC 0.0450842200278f

// lgkm-only barrier: LDS writes visible + wave sync; vmcnt (global loads in
// flight to wave-private registers) NOT drained -- prefetches survive it.
#define HBAR() asm volatile("s_waitcnt lgkmcnt(0)\n\ts_barrier" ::: "memory")

__device__ __forceinline__ u16 f2bf(float f) {
    bf16 h = __float2bfloat16(f);
    u16 u; __builtin_memcpy(&u, &h, 2); return u;
}

// ---------------- 4x weight transpose+convert (1024x1024 each) ---------------
__global__ __launch_bounds__(256)
void transpose_w4(const float* __restrict__ s0, const float* __restrict__ s1,
                  const float* __restrict__ s2, const float* __restrict__ s3,
                  u16* __restrict__ d0, u16* __restrict__ d1,
                  u16* __restrict__ d2, u16* __restrict__ d3) {
    const float* src = (blockIdx.z == 0) ? s0 : (blockIdx.z == 1) ? s1
                     : (blockIdx.z == 2) ? s2 : s3;
    u16* dst = (blockIdx.z == 0) ? d0 : (blockIdx.z == 1) ? d1
             : (blockIdx.z == 2) ? d2 : d3;
    __shared__ float t[64][65];
    const int r0 = blockIdx.y * 64, c0 = blockIdx.x * 64;
    const int tr = threadIdx.x >> 6, tc = threadIdx.x & 63;
#pragma unroll
    for (int i = 0; i < 16; i++)
        t[tr + i * 4][tc] = src[(size_t)(r0 + tr + i * 4) * 1024 + c0 + tc];
    __syncthreads();
#pragma unroll
    for (int i = 0; i < 16; i++)
        dst[(size_t)(c0 + tr + i * 4) * 1024 + r0 + tc] = f2bf(t[tc][tr + i * 4]);
}

// ---------------- generic weight transpose: src fp32 [R][C] -> bf16 [C][R] ---
__global__ __launch_bounds__(256)
void transpose_w(const float* __restrict__ src, u16* __restrict__ dst,
                 int R, int C) {
    __shared__ float t[64][65];
    const int r0 = blockIdx.y * 64, c0 = blockIdx.x * 64;
    const int tr = threadIdx.x >> 6, tc = threadIdx.x & 63;
#pragma unroll
    for (int i = 0; i < 16; i++)
        t[tr + i * 4][tc] = src[(size_t)(r0 + tr + i * 4) * C + c0 + tc];
    __syncthreads();
#pragma unroll
    for (int i = 0; i < 16; i++)
        dst[(size_t)(c0 + tr + i * 4) * R + r0 + tc] = f2bf(t[tc][tr + i * 4]);
}

// ---------------- LayerNorm: one block per row of E=1024 ---------------------
__global__ __launch_bounds__(256)
void ln_kernel(const float* __restrict__ x, const float* __restrict__ g,
               const float* __restrict__ b, u16* __restrict__ out) {
    const int row = blockIdx.x;
    const int tid = threadIdx.x;
    const float* xp = x + (size_t)row * En;
    float v[4];
    float s = 0.f, sq = 0.f;
#pragma unroll
    for (int i = 0; i < 4; i++) {
        v[i] = xp[tid + i * 256];
        s += v[i];
        sq += v[i] * v[i];
    }
    __shared__ float rs[256], rq[256];
    rs[tid] = s; rq[tid] = sq;
    __syncthreads();
    for (int st = 128; st > 0; st >>= 1) {
        if (tid < st) { rs[tid] += rs[tid + st]; rq[tid] += rq[tid + st]; }
        __syncthreads();
    }
    const float mu  = rs[0] * (1.0f / En);
    const float var = rq[0] * (1.0f / En) - mu * mu;
    const float inv = rsqrtf(var + 1e-5f);
#pragma unroll
    for (int i = 0; i < 4; i++) {
        const int c = tid + i * 256;
        out[(size_t)row * En + c] = f2bf((v[i] - mu) * inv * g[c] + b[c]);
    }
}

// ---------------- m97-style GEMM + XOR swizzle -------------------------------
// C[4096,N] = A(bf16 [M][K]) @ Wt(bf16 [N][K])^T. TM x 128 tile, BK=32, 4 waves.
// SCQ: multiply C by QSC for n-tiles < 1024 (Q pre-scale for flash).
template<int TM, int HAS_BIAS, int RELU, int HAS_RES, int OUT_F32, int SCQ>
__global__ __launch_bounds__(256)
void gemm_bt(const u16* __restrict__ A, int ldA,
             const u16* __restrict__ Wt, int ldW,
             const float* __restrict__ bias, const float* __restrict__ res,
             void* __restrict__ Cout, int ldC, int Kd) {
    constexpr int IF = TM / 32;          // i-frags per wave
    __shared__ __align__(16) u16 As[TM * 32];
    __shared__ __align__(16) u16 Bs[128 * 32];
    const int tid  = threadIdx.x;
    const int lane = tid & 63, wv = tid >> 6;
    const int quad = lane >> 4, l16 = lane & 15;
    const int m0 = blockIdx.y * TM, n0 = blockIdx.x * 128;
    const int rw = (wv >> 1) * (TM / 2), cw = (wv & 1) * 64;
    const int lr  = lane >> 2;                         // row within 16-row chunk
    const int gsw = ((lane & 3) ^ ((lane >> 3) & 3)) * 8;  // swizzled src colgrp
    const int psw = (quad ^ ((l16 >> 1) & 3)) * 8;     // swizzled read colgrp

    f32x4 acc[IF][4] = {};

    for (int kt = 0; kt < Kd; kt += 32) {
        __syncthreads();
#pragma unroll
        for (int t = 0; t < TM / 64; t++) {
            const int row = wv * (TM / 4) + t * 16;
            __builtin_amdgcn_global_load_lds(
                (cg_void*)(const void*)&A[(size_t)(m0 + row + lr) * ldA + kt + gsw],
                (lds_void*)(void*)&As[row * 32], 16, 0, 0);
        }
#pragma unroll
        for (int t = 0; t < 2; t++) {
            const int row = wv * 32 + t * 16;
            __builtin_amdgcn_global_load_lds(
                (cg_void*)(const void*)&Wt[(size_t)(n0 + row + lr) * ldW + kt + gsw],
                (lds_void*)(void*)&Bs[row * 32], 16, 0, 0);
        }
        __syncthreads();

        short8 af[IF], bfr[4];
#pragma unroll
        for (int i = 0; i < IF; i++)
            af[i] = *(const short8*)&As[(rw + i * 16 + l16) * 32 + psw];
#pragma unroll
        for (int j = 0; j < 4; j++)
            bfr[j] = *(const short8*)&Bs[(cw + j * 16 + l16) * 32 + psw];
#pragma unroll
        for (int i = 0; i < IF; i++)
#pragma unroll
            for (int j = 0; j < 4; j++)
                acc[i][j] = __builtin_amdgcn_mfma_f32_16x16x32_bf16(
                    af[i], bfr[j], acc[i][j], 0, 0, 0);
    }

    const float qscale = (SCQ && n0 < 1024) ? QSC : 1.0f;
#pragma unroll
    for (int i = 0; i < IF; i++) {
#pragma unroll
        for (int r = 0; r < 4; r++) {
            const int gm = m0 + rw + i * 16 + quad * 4 + r;
#pragma unroll
            for (int j = 0; j < 4; j++) {
                const int gn = n0 + cw + j * 16 + l16;
                float c = acc[i][j][r];
                if (HAS_BIAS) c += bias[gn];
                if (RELU) c = fmaxf(c, 0.f);
                if (HAS_RES) c += res[(size_t)gm * ldC + gn];
                if (SCQ) c *= qscale;
                if (OUT_F32) ((float*)Cout)[(size_t)gm * ldC + gn] = c;
                else         ((u16*)Cout)[(size_t)gm * ldC + gn] = f2bf(c);
            }
        }
    }
}

// ---------------- Flash attention v5 -----------------------------------------
// 128-wide K rounds amortize softmax VALU over 2x keys. Transposed-S, per-lane
// q stats, Q pre-scaled by QSC in GEMM. Paired q-tiles {x,31-x}: uniform
// 15 full128 + 1 masked128 + 1 masked64 rounds per block.
template<int NI, bool MASK>
__device__ __forceinline__ void attn_round(
    const u16* __restrict__ Ks, const u16* __restrict__ Vt,
    u16* __restrict__ Psw, const short8* qf, f32x4* ot,
    float& m2, float& lrow, int quad, int l16, int qloc) {
    // S^T strip: St[key = i*16+quad*4+r][q = l16]
    f32x4 st[NI];
#pragma unroll
    for (int i = 0; i < NI; i++) st[i] = (f32x4){0.f, 0.f, 0.f, 0.f};
#pragma unroll
    for (int ks = 0; ks < 2; ks++)
#pragma unroll
        for (int i = 0; i < NI; i++) {
            short8 kf = *(const short8*)&Ks[(i * 16 + l16) * 72 + ks * 32 + quad * 8];
            st[i] = __builtin_amdgcn_mfma_f32_16x16x32_bf16(kf, qf[ks], st[i], 0, 0, 0);
        }
    // per-lane online softmax (log2 domain; Q was pre-scaled)
    float tmax = -INFINITY;
#pragma unroll
    for (int i = 0; i < NI; i++)
#pragma unroll
        for (int r = 0; r < 4; r++) {
            float s = st[i][r];
            if (MASK && (i * 16 + quad * 4 + r > qloc)) s = -INFINITY;
            st[i][r] = s;
            tmax = fmaxf(tmax, s);
        }
    tmax = fmaxf(tmax, __shfl_xor(tmax, 16));
    tmax = fmaxf(tmax, __shfl_xor(tmax, 32));
    const float mnew = fmaxf(m2, tmax);
    const float alpha = exp2f(m2 - mnew);
    m2 = mnew;
    float psum = 0.f;
#pragma unroll
    for (int i = 0; i < NI; i++)
#pragma unroll
        for (int r = 0; r < 4; r++) {
            const float e = exp2f(st[i][r] - mnew);
            st[i][r] = e;
            psum += e;
        }
    psum += __shfl_xor(psum, 16);
    psum += __shfl_xor(psum, 32);
    lrow = lrow * alpha + psum;
#pragma unroll
    for (int i = 0; i < 4; i++) ot[i] *= alpha;
    // P^T (C-layout) -> Ps[q=l16][key], b64-packed (4 consecutive keys)
#pragma unroll
    for (int i = 0; i < NI; i++) {
        uint2 w;
        w.x = (u32)f2bf(st[i][0]) | ((u32)f2bf(st[i][1]) << 16);
        w.y = (u32)f2bf(st[i][2]) | ((u32)f2bf(st[i][3]) << 16);
        *(uint2*)&Psw[l16 * 136 + i * 16 + quad * 4] = w;
    }
    asm volatile("s_waitcnt lgkmcnt(0)" ::: "memory");
    // O^T strip += V^T @ P^T
#pragma unroll
    for (int ks = 0; ks < NI / 2; ks++) {
        short8 pf = *(const short8*)&Psw[l16 * 136 + ks * 32 + quad * 8];
#pragma unroll
        for (int i = 0; i < 4; i++) {
            short8 vf = *(const short8*)&Vt[(i * 16 + l16) * 136 + ks * 32 + quad * 8];
            ot[i] = __builtin_amdgcn_mfma_f32_16x16x32_bf16(vf, pf, ot[i], 0, 0, 0);
        }
    }
}

__global__ __launch_bounds__(256)
void flash_attn(u16* __restrict__ QKV) {
    const int hh = blockIdx.y, bb = blockIdx.z;
    const int tid  = threadIdx.x;
    const int lane = tid & 63, wv = tid >> 6;
    const int quad = lane >> 4, l16 = lane & 15;

    __shared__ __align__(16) u16 Ks[128 * 72];      // [key][dh], stride 72
    __shared__ __align__(16) u16 Vt[64 * 136];      // [dh][key], stride 136
    __shared__ __align__(16) u16 Ps[4][16 * 136];   // per-wave [q][key]

    const size_t rowbase = (size_t)(bb * Tn) * QKVLD;
    // K staging 128 rows: 2 thr/row, 4 colgroups each {g,g+2,g+4,g+6}
    const int k_r = tid >> 1, k_g = tid & 1;
    // V staging 128 keys: key pair kk, 16 dh rows per wave
    const int v_kk = (tid & 63) * 2, v_dh = wv * 16;
    // 64-key staging
    const int k64_r = tid >> 2, k64_g = tid & 3;
    const int v64_kk = (tid & 31) * 2, v64_dh = (tid >> 5) * 8;

    uint4 kr0, kr1, kr2, kr3, vr0, vr1, vr2, vr3;

    auto prefetch128 = [&](int kb) {
        const size_t kbb = rowbase + (size_t)(kb + k_r) * QKVLD + 1024 + hh * 64;
        kr0 = *(const uint4*)&QKV[kbb + k_g * 8];
        kr1 = *(const uint4*)&QKV[kbb + (k_g + 2) * 8];
        kr2 = *(const uint4*)&QKV[kbb + (k_g + 4) * 8];
        kr3 = *(const uint4*)&QKV[kbb + (k_g + 6) * 8];
        const size_t vb0 = rowbase + (size_t)(kb + v_kk) * QKVLD + 2048 + hh * 64 + v_dh;
        vr0 = *(const uint4*)&QKV[vb0];
        vr1 = *(const uint4*)&QKV[vb0 + 8];
        vr2 = *(const uint4*)&QKV[vb0 + QKVLD];
        vr3 = *(const uint4*)&QKV[vb0 + QKVLD + 8];
    };
    auto write128 = [&]() {
        *(uint4*)&Ks[k_r * 72 + k_g * 8]       = kr0;
        *(uint4*)&Ks[k_r * 72 + (k_g + 2) * 8] = kr1;
        *(uint4*)&Ks[k_r * 72 + (k_g + 4) * 8] = kr2;
        *(uint4*)&Ks[k_r * 72 + (k_g + 6) * 8] = kr3;
        u16 va[16], vb[16];
        *(uint4*)&va[0] = vr0; *(uint4*)&va[8] = vr1;
        *(uint4*)&vb[0] = vr2; *(uint4*)&vb[8] = vr3;
#pragma unroll
        for (int j = 0; j < 16; j++) {
            const u32 w = (u32)va[j] | ((u32)vb[j] << 16);
            *(u32*)&Vt[(v_dh + j) * 136 + v_kk] = w;
        }
    };
    auto stage64 = [&](int kb) {
        const size_t kbb = rowbase + (size_t)(kb + k64_r) * QKVLD + 1024 + hh * 64;
        *(uint4*)&Ks[k64_r * 72 + k64_g * 8]       = *(const uint4*)&QKV[kbb + k64_g * 8];
        *(uint4*)&Ks[k64_r * 72 + (k64_g + 4) * 8] = *(const uint4*)&QKV[kbb + (k64_g + 4) * 8];
        const size_t vb0 = rowbase + (size_t)(kb + v64_kk) * QKVLD + 2048 + hh * 64 + v64_dh;
        uint4 p0 = *(const uint4*)&QKV[vb0];
        uint4 p1 = *(const uint4*)&QKV[vb0 + QKVLD];
        u16 pa[8], pb[8];
        *(uint4*)&pa[0] = p0; *(uint4*)&pb[0] = p1;
#pragma unroll
        for (int j = 0; j < 8; j++) {
            const u32 w = (u32)pa[j] | ((u32)pb[j] << 16);
            *(u32*)&Vt[(v64_dh + j) * 136 + v64_kk] = w;
        }
    };

    for (int qsel = 0; qsel < 2; qsel++) {
        const int qt = qsel ? (31 - blockIdx.x) : blockIdx.x;
        const int n128 = (qt >> 1) + (qt & 1);   // 128-wide rounds
        const int qloc16 = wv * 16 + l16;        // q within tile (per-lane)

        // Q fragment direct from global (per-lane; 2x per block, negligible)
        const size_t qrow = rowbase + (size_t)(qt * 64 + qloc16) * QKVLD + hh * 64;
        short8 qf[2];
        qf[0] = *(const short8*)&QKV[qrow + quad * 8];
        qf[1] = *(const short8*)&QKV[qrow + 32 + quad * 8];

        f32x4 ot[4] = {};                 // O^T: dh=i*16+quad*4+r, q=l16
        float m2 = -INFINITY, lrow = 0.f;

        HBAR();   // prior phase readers done
        if (n128 > 0) {
            prefetch128(0);
            write128();
            if (n128 > 1) prefetch128(128);
            HBAR();   // tile 0 ready
            for (int f = 0; f < n128; f++) {
                const bool maskthis = (qt & 1) && (f == n128 - 1);
                if (maskthis)
                    attn_round<8, true>(Ks, Vt, &Ps[wv][0], qf, ot, m2, lrow,
                                        quad, l16, qloc16 + 64);
                else
                    attn_round<8, false>(Ks, Vt, &Ps[wv][0], qf, ot, m2, lrow,
                                         quad, l16, 0);
                HBAR();   // readers done
                if (f + 1 < n128) {
                    write128();
                    if (f + 2 < n128) prefetch128((f + 2) * 128);
                    HBAR();
                } else if (!(qt & 1)) {
                    stage64(qt * 64);
                    HBAR();
                }
            }
            if (!(qt & 1))
                attn_round<4, true>(Ks, Vt, &Ps[wv][0], qf, ot, m2, lrow,
                                    quad, l16, qloc16);
        } else {
            // qt == 0: single masked 64-key round
            stage64(0);
            HBAR();
            attn_round<4, true>(Ks, Vt, &Ps[wv][0], qf, ot, m2, lrow,
                                quad, l16, qloc16);
        }

        // write O over Q slice: q = wv*16+l16, dh = i*16+quad*4+r
        const float linv = 1.0f / lrow;
        const size_t obase = rowbase + (size_t)(qt * 64 + qloc16) * QKVLD + hh * 64;
#pragma unroll
        for (int i = 0; i < 4; i++) {
            ushort4 o4;
            o4.x = f2bf(ot[i][0] * linv);
            o4.y = f2bf(ot[i][1] * linv);
            o4.z = f2bf(ot[i][2] * linv);
            o4.w = f2bf(ot[i][3] * linv);
            *(ushort4*)&QKV[obase + i * 16 + quad * 4] = o4;
        }
    }
}

// ---------------- Launcher ---------------------------------------------------
// Inputs fp32, output fp32 [B,T,E].
extern "C" void kernel_launch(void* const* d_in, const int* in_sizes, int n_in,
                              void* d_out, int out_size, void* d_ws, size_t ws_size,
                              hipStream_t stream) {
    const float* x   = (const float*)d_in[0];
    const float* Wq  = (const float*)d_in[1];
    const float* Wk  = (const float*)d_in[2];
    const float* Wv  = (const float*)d_in[3];
    const float* Wo  = (const float*)d_in[4];
    const float* bo  = (const float*)d_in[5];
    const float* W1  = (const float*)d_in[6];
    const float* b1  = (const float*)d_in[7];
    const float* W2  = (const float*)d_in[8];
    const float* b2  = (const float*)d_in[9];
    const float* g1  = (const float*)d_in[10];
    const float* be1 = (const float*)d_in[11];
    const float* g2  = (const float*)d_in[12];
    const float* be2 = (const float*)d_in[13];

    // Workspace (40 MB):
    //   [ 0,24M): QKV bf16 [4096][3072]; dead after O-proj -> F1 [0,16M),
    //             W2T bf16 [1024][4096] at [16,24M)
    //   [24,40M): X1 fp32 [4096][1024]
    // d_out (16 MB fp32): [0,8M) h bf16; [8,16M) early WqkvT+WoT, late W1T.
    char* wsb = (char*)d_ws;
    u16*   QKV = (u16*)wsb;
    u16*   F1  = (u16*)wsb;                              // [4096][2048]
    u16*   W2T = (u16*)(wsb + 16u * 1024 * 1024);        // [1024][4096]
    float* X1  = (float*)(wsb + 24u * 1024 * 1024);
    u16*   h     = (u16*)d_out;
    u16*   WT    = (u16*)((char*)d_out + 8u * 1024 * 1024);
    u16*   WqkvT = WT;                                   // [3072][1024]
    u16*   WoT   = WT + 3u * 1024 * 1024;                // [1024][1024]
    u16*   W1T   = WT;                                   // [4096][1024] (late)

    // 0. early weight transposes (fp32 -> bf16, B^T layout)
    transpose_w4<<<dim3(16, 16, 4), 256, 0, stream>>>(
        Wq, Wk, Wv, Wo,
        WqkvT, WqkvT + 1024u * 1024, WqkvT + 2048u * 1024, WoT);

    // 1. h = LN(x, g1, be1)
    ln_kernel<<<Mn, 256, 0, stream>>>(x, g1, be1, h);

    // 2. QKV = h @ [Wq|Wk|Wv]; Q columns pre-scaled by QSC (SCQ=1)
    gemm_bt<128, 0, 0, 0, 0, 1><<<dim3(24, 32), 256, 0, stream>>>(
        h, En, WqkvT, En, nullptr, nullptr, QKV, QKVLD, En);

    // 3. O = causal_softmax(Q K^T) V   (in place over Q cols)
    flash_attn<<<dim3(16, Hn, Bn), 256, 0, stream>>>(QKV);

    // 4. X1 = x + O @ Wo + bo   (fp32)
    gemm_bt<64, 1, 0, 1, 1, 0><<<dim3(8, 64), 256, 0, stream>>>(
        QKV, QKVLD, WoT, En, bo, x, X1, En, En);

    // 5. late weight transposes (QKV + WT regions now dead)
    transpose_w<<<dim3(64, 16), 256, 0, stream>>>(W1, W1T, 1024, 4096);
    transpose_w<<<dim3(16, 64), 256, 0, stream>>>(W2, W2T, 4096, 1024);

    // 6. h2 = LN(X1, g2, be2)
    ln_kernel<<<Mn, 256, 0, stream>>>(X1, g2, be2, h);

    // 7. FFN in 2 halves of 2048; X1 accumulates in place; final -> d_out fp32
    gemm_bt<128, 1, 1, 0, 0, 0><<<dim3(16, 32), 256, 0, stream>>>(
        h, En, W1T, En, b1, nullptr, F1, 2048, En);
    gemm_bt<64, 0, 0, 1, 1, 0><<<dim3(8, 64), 256, 0, stream>>>(
        F1, 2048, W2T, DFFn, nullptr, X1, X1, En, 2048);
    gemm_bt<128, 1, 1, 0, 0, 0><<<dim3(16, 32), 256, 0, stream>>>(
        h, En, W1T + 2048u * 1024, En, b1 + 2048, nullptr, F1, 2048, En);
    gemm_bt<64, 1, 0, 1, 1, 0><<<dim3(8, 64), 256, 0, stream>>>(
        F1, 2048, W2T + 2048, DFFn, b2, X1, (float*)d_out, En, 2048);
}

// Round 11
// 392.098 us; speedup vs baseline: 1.0197x; 1.0197x over previous
//
#include <hip/hip_runtime.h>
#include <hip/hip_bf16.h>
#include <math.h>

// Problem constants
#define Bn 2
#define Tn 2048
#define En 1024
#define Hn 16
#define DFFn 4096
#define Mn (Bn*Tn)   // 4096 rows
#define QKVLD 3072   // fused QKV leading dim

typedef __hip_bfloat16 bf16;
typedef unsigned short u16;
typedef unsigned int u32;
typedef __attribute__((ext_vector_type(8))) short short8;
typedef __attribute__((ext_vector_type(4))) float f32x4;

typedef __attribute__((address_space(1))) const void cg_void;
typedef __attribute__((address_space(3))) void lds_void;

// Q pre-scale folded into QKV GEMM: E^-0.5 * log2(e)
#define QSC 0.0450842200278f

// lgkm-only barrier: LDS writes visible + wave sync; vmcnt (global loads in
// flight to wave-private registers) NOT drained -- prefetches survive it.
#define HBAR() asm volatile("s_waitcnt lgkmcnt(0)\n\ts_barrier" ::: "memory")

__device__ __forceinline__ u16 f2bf(float f) {
    bf16 h = __float2bfloat16(f);
    u16 u; __builtin_memcpy(&u, &h, 2); return u;
}
__device__ __forceinline__ float bf2f(u16 u) {
    u32 x = ((u32)u) << 16; float f; __builtin_memcpy(&f, &x, 4); return f;
}

// ---------------- 4x weight transpose+convert (1024x1024 each) ---------------
__global__ __launch_bounds__(256)
void transpose_w4(const float* __restrict__ s0, const float* __restrict__ s1,
                  const float* __restrict__ s2, const float* __restrict__ s3,
                  u16* __restrict__ d0, u16* __restrict__ d1,
                  u16* __restrict__ d2, u16* __restrict__ d3) {
    const float* src = (blockIdx.z == 0) ? s0 : (blockIdx.z == 1) ? s1
                     : (blockIdx.z == 2) ? s2 : s3;
    u16* dst = (blockIdx.z == 0) ? d0 : (blockIdx.z == 1) ? d1
             : (blockIdx.z == 2) ? d2 : d3;
    __shared__ float t[64][65];
    const int r0 = blockIdx.y * 64, c0 = blockIdx.x * 64;
    const int tr = threadIdx.x >> 6, tc = threadIdx.x & 63;
#pragma unroll
    for (int i = 0; i < 16; i++)
        t[tr + i * 4][tc] = src[(size_t)(r0 + tr + i * 4) * 1024 + c0 + tc];
    __syncthreads();
#pragma unroll
    for (int i = 0; i < 16; i++)
        dst[(size_t)(c0 + tr + i * 4) * 1024 + r0 + tc] = f2bf(t[tc][tr + i * 4]);
}

// ---------------- generic weight transpose: src fp32 [R][C] -> bf16 [C][R] ---
__global__ __launch_bounds__(256)
void transpose_w(const float* __restrict__ src, u16* __restrict__ dst,
                 int R, int C) {
    __shared__ float t[64][65];
    const int r0 = blockIdx.y * 64, c0 = blockIdx.x * 64;
    const int tr = threadIdx.x >> 6, tc = threadIdx.x & 63;
#pragma unroll
    for (int i = 0; i < 16; i++)
        t[tr + i * 4][tc] = src[(size_t)(r0 + tr + i * 4) * C + c0 + tc];
    __syncthreads();
#pragma unroll
    for (int i = 0; i < 16; i++)
        dst[(size_t)(c0 + tr + i * 4) * R + r0 + tc] = f2bf(t[tc][tr + i * 4]);
}

// ---------------- V copy-transpose: QKV V-cols -> Vg[bh][dh=64][tok=2048] ----
__global__ __launch_bounds__(256)
void vcopy_t(const u16* __restrict__ QKV, u16* __restrict__ Vg) {
    const int bh = blockIdx.z;          // bb*16+hh
    const int t0 = blockIdx.y * 64;     // token tile
    __shared__ u16 t[64][65];
    const int tr = threadIdx.x >> 6, tc = threadIdx.x & 63;
    const u16* src = QKV + (size_t)(bh >> 4) * 2048 * QKVLD + 2048 + (bh & 15) * 64;
#pragma unroll
    for (int i = 0; i < 16; i++)
        t[tr + i * 4][tc] = src[(size_t)(t0 + tr + i * 4) * QKVLD + tc];  // [tokl][dh]
    __syncthreads();
    u16* dst = Vg + (size_t)bh * 64 * 2048;
#pragma unroll
    for (int i = 0; i < 16; i++)
        dst[(size_t)(tr + i * 4) * 2048 + t0 + tc] = t[tc][tr + i * 4];
}

// ---------------- LayerNorm: one block per row of E=1024 ---------------------
template<typename AT>
__global__ __launch_bounds__(256)
void ln_kernel(const AT* __restrict__ x, const float* __restrict__ g,
               const float* __restrict__ b, u16* __restrict__ out) {
    const int row = blockIdx.x;
    const int tid = threadIdx.x;
    const AT* xp = x + (size_t)row * En;
    float v[4];
    float s = 0.f, sq = 0.f;
#pragma unroll
    for (int i = 0; i < 4; i++) {
        if constexpr (sizeof(AT) == 2) v[i] = bf2f(xp[tid + i * 256]);
        else                           v[i] = (float)xp[tid + i * 256];
        s += v[i];
        sq += v[i] * v[i];
    }
    __shared__ float rs[256], rq[256];
    rs[tid] = s; rq[tid] = sq;
    __syncthreads();
    for (int st = 128; st > 0; st >>= 1) {
        if (tid < st) { rs[tid] += rs[tid + st]; rq[tid] += rq[tid + st]; }
        __syncthreads();
    }
    const float mu  = rs[0] * (1.0f / En);
    const float var = rq[0] * (1.0f / En) - mu * mu;
    const float inv = rsqrtf(var + 1e-5f);
#pragma unroll
    for (int i = 0; i < 4; i++) {
        const int c = tid + i * 256;
        out[(size_t)row * En + c] = f2bf((v[i] - mu) * inv * g[c] + b[c]);
    }
}

// ---------------- m97-style GEMM + XOR swizzle -------------------------------
// C[4096,N] = A(bf16 [M][K]) @ Wt(bf16 [N][K])^T. TM x 128 tile, BK=32, 4 waves.
// RES: 0 none / 1 fp32 / 2 bf16. OUT_F32: out dtype. SCQ: Q pre-scale n0<1024.
template<int TM, int HAS_BIAS, int RELU, int RES, int OUT_F32, int SCQ>
__global__ __launch_bounds__(256)
void gemm_bt(const u16* __restrict__ A, int ldA,
             const u16* __restrict__ Wt, int ldW,
             const float* __restrict__ bias, const void* __restrict__ res,
             void* __restrict__ Cout, int ldC, int Kd) {
    constexpr int IF = TM / 32;          // i-frags per wave
    __shared__ __align__(16) u16 As[TM * 32];
    __shared__ __align__(16) u16 Bs[128 * 32];
    const int tid  = threadIdx.x;
    const int lane = tid & 63, wv = tid >> 6;
    const int quad = lane >> 4, l16 = lane & 15;
    const int m0 = blockIdx.y * TM, n0 = blockIdx.x * 128;
    const int rw = (wv >> 1) * (TM / 2), cw = (wv & 1) * 64;
    const int lr  = lane >> 2;                         // row within 16-row chunk
    const int gsw = ((lane & 3) ^ ((lane >> 3) & 3)) * 8;  // swizzled src colgrp
    const int psw = (quad ^ ((l16 >> 1) & 3)) * 8;     // swizzled read colgrp

    f32x4 acc[IF][4] = {};

    for (int kt = 0; kt < Kd; kt += 32) {
        __syncthreads();
#pragma unroll
        for (int t = 0; t < TM / 64; t++) {
            const int row = wv * (TM / 4) + t * 16;
            __builtin_amdgcn_global_load_lds(
                (cg_void*)(const void*)&A[(size_t)(m0 + row + lr) * ldA + kt + gsw],
                (lds_void*)(void*)&As[row * 32], 16, 0, 0);
        }
#pragma unroll
        for (int t = 0; t < 2; t++) {
            const int row = wv * 32 + t * 16;
            __builtin_amdgcn_global_load_lds(
                (cg_void*)(const void*)&Wt[(size_t)(n0 + row + lr) * ldW + kt + gsw],
                (lds_void*)(void*)&Bs[row * 32], 16, 0, 0);
        }
        __syncthreads();

        short8 af[IF], bfr[4];
#pragma unroll
        for (int i = 0; i < IF; i++)
            af[i] = *(const short8*)&As[(rw + i * 16 + l16) * 32 + psw];
#pragma unroll
        for (int j = 0; j < 4; j++)
            bfr[j] = *(const short8*)&Bs[(cw + j * 16 + l16) * 32 + psw];
#pragma unroll
        for (int i = 0; i < IF; i++)
#pragma unroll
            for (int j = 0; j < 4; j++)
                acc[i][j] = __builtin_amdgcn_mfma_f32_16x16x32_bf16(
                    af[i], bfr[j], acc[i][j], 0, 0, 0);
    }

    const float qscale = (SCQ && n0 < 1024) ? QSC : 1.0f;
#pragma unroll
    for (int i = 0; i < IF; i++) {
#pragma unroll
        for (int r = 0; r < 4; r++) {
            const int gm = m0 + rw + i * 16 + quad * 4 + r;
#pragma unroll
            for (int j = 0; j < 4; j++) {
                const int gn = n0 + cw + j * 16 + l16;
                float c = acc[i][j][r];
                if (HAS_BIAS) c += bias[gn];
                if (RELU) c = fmaxf(c, 0.f);
                if (RES == 1) c += ((const float*)res)[(size_t)gm * ldC + gn];
                if (RES == 2) c += bf2f(((const u16*)res)[(size_t)gm * ldC + gn]);
                if (SCQ) c *= qscale;
                if (OUT_F32) ((float*)Cout)[(size_t)gm * ldC + gn] = c;
                else         ((u16*)Cout)[(size_t)gm * ldC + gn] = f2bf(c);
            }
        }
    }
}

// ---------------- Flash attention pass 1 (split-K, v6) -----------------------
// Grid (32,16,2): x = pair*2+half. Pair {pr,31-pr}; half h takes kt = h,h+2,...
// Transposed-S, per-lane q stats, double-buffered K/V (register relay, one
// lgkm-only barrier per round). K from QKV [key][dh]; V from Vg [dh][tok]
// (pre-transposed) -- both staged with identical b128 relay, XOR-swizzled
// unpadded stride-64 LDS (40 KB total -> 4 blocks/CU).
// Partials: half0 -> Op0 [4096][1024]; half1 -> QKV V-cols (ld 3072, dead).
// Stats (log2 domain m, l) per (half, row, head) -> stats buffer.
__global__ __launch_bounds__(256)
void flash_pass1(const u16* __restrict__ QKV, const u16* __restrict__ Vg,
                 u16* __restrict__ Op0, u16* __restrict__ Op1qkv,
                 float* __restrict__ stats) {
    const int pr = blockIdx.x >> 1, half = blockIdx.x & 1;
    const int hh = blockIdx.y, bb = blockIdx.z;
    const int tid  = threadIdx.x;
    const int lane = tid & 63, wv = tid >> 6;
    const int quad = lane >> 4, l16 = lane & 15;

    __shared__ __align__(16) u16 Ks[2][64 * 64];
    __shared__ __align__(16) u16 Vt[2][64 * 64];
    __shared__ __align__(16) u16 Ps[4][16 * 64];

    const size_t rowbase = (size_t)(bb * Tn) * QKVLD;
    const u16* Vgh = Vg + (size_t)(bb * Hn + hh) * 64 * 2048;

    // staging decomp: row sr, two phys 16B-groups p0/p1, logical sources g0/g1
    const int sr = tid >> 2;
    const int p0 = (tid & 3) | ((sr & 1) << 2);
    const int p1 = p0 ^ 4;
    const int g0 = p0 ^ (sr & 7), g1 = p1 ^ (sr & 7);
    const int lsw = l16 & 7;                       // fragment-read row swizzle

    uint4 kA, kB, vA, vB;
    auto prefetch = [&](int kt) {
        const size_t kb = rowbase + (size_t)(kt * 64 + sr) * QKVLD + 1024 + hh * 64;
        kA = *(const uint4*)&QKV[kb + g0 * 8];
        kB = *(const uint4*)&QKV[kb + g1 * 8];
        const size_t vb = (size_t)sr * 2048 + kt * 64;
        vA = *(const uint4*)&Vgh[vb + g0 * 8];
        vB = *(const uint4*)&Vgh[vb + g1 * 8];
    };
    auto writebuf = [&](int buf) {
        *(uint4*)&Ks[buf][sr * 64 + p0 * 8] = kA;
        *(uint4*)&Ks[buf][sr * 64 + p1 * 8] = kB;
        *(uint4*)&Vt[buf][sr * 64 + p0 * 8] = vA;
        *(uint4*)&Vt[buf][sr * 64 + p1 * 8] = vB;
    };

    for (int qsel = 0; qsel < 2; qsel++) {
        const int qt = qsel ? (31 - pr) : pr;
        const int nk = (qt >= half) ? ((qt - half) >> 1) + 1 : 0;
        const int qrow = qt * 64 + wv * 16 + l16;        // row within batch
        const int grow = bb * Tn + qrow;                 // global 4096-row idx

        f32x4 ot[4] = {};
        float m2 = -INFINITY, lrow = 0.f;

        HBAR();   // previous q-tile's LDS readers done
        if (nk > 0) {
            // Q fragment direct from global (Q cols pre-scaled by QSC)
            const u16* qp = QKV + rowbase + (size_t)qrow * QKVLD + hh * 64;
            short8 qf[2];
            qf[0] = *(const short8*)&qp[quad * 8];
            qf[1] = *(const short8*)&qp[32 + quad * 8];

            prefetch(half);
            writebuf(0);
            if (nk > 1) prefetch(half + 2);
            HBAR();   // buf0 ready; prefetch stays in flight

            const bool hasdiag = ((qt ^ half) & 1) == 0;  // last round masked?
            for (int f = 0; f < nk; f++) {
                const int cur = f & 1;

                // S^T strip: St[key=i*16+quad*4+r][q=l16]
                f32x4 st[4] = {};
#pragma unroll
                for (int ks = 0; ks < 2; ks++)
#pragma unroll
                    for (int i = 0; i < 4; i++) {
                        short8 kf = *(const short8*)&Ks[cur][(i * 16 + l16) * 64 +
                                     (((ks * 4 + quad) ^ lsw) * 8)];
                        st[i] = __builtin_amdgcn_mfma_f32_16x16x32_bf16(
                            kf, qf[ks], st[i], 0, 0, 0);
                    }

                // per-lane online softmax (log2 domain)
                float tmax = -INFINITY;
                if (hasdiag && f == nk - 1) {            // diagonal tile
                    const int qloc = wv * 16 + l16;
#pragma unroll
                    for (int i = 0; i < 4; i++)
#pragma unroll
                        for (int r = 0; r < 4; r++) {
                            float s = st[i][r];
                            if (i * 16 + quad * 4 + r > qloc) s = -INFINITY;
                            st[i][r] = s;
                            tmax = fmaxf(tmax, s);
                        }
                } else {
#pragma unroll
                    for (int i = 0; i < 4; i++)
#pragma unroll
                        for (int r = 0; r < 4; r++)
                            tmax = fmaxf(tmax, st[i][r]);
                }
                tmax = fmaxf(tmax, __shfl_xor(tmax, 16));
                tmax = fmaxf(tmax, __shfl_xor(tmax, 32));

                const float mnew = fmaxf(m2, tmax);
                const float alpha = exp2f(m2 - mnew);
                m2 = mnew;
                float psum = 0.f;
#pragma unroll
                for (int i = 0; i < 4; i++)
#pragma unroll
                    for (int r = 0; r < 4; r++) {
                        const float e = exp2f(st[i][r] - mnew);
                        st[i][r] = e;
                        psum += e;
                    }
                psum += __shfl_xor(psum, 16);
                psum += __shfl_xor(psum, 32);
                lrow = lrow * alpha + psum;
#pragma unroll
                for (int i = 0; i < 4; i++) ot[i] *= alpha;

                // P^T (C-layout) -> Ps[q=l16][key], b64-packed, XOR-swizzled
#pragma unroll
                for (int i = 0; i < 4; i++) {
                    uint2 w;
                    w.x = (u32)f2bf(st[i][0]) | ((u32)f2bf(st[i][1]) << 16);
                    w.y = (u32)f2bf(st[i][2]) | ((u32)f2bf(st[i][3]) << 16);
                    const int g = (i * 2 + (quad >> 1)) ^ lsw;
                    *(uint2*)&Ps[wv][l16 * 64 + g * 8 + (quad & 1) * 4] = w;
                }
                asm volatile("s_waitcnt lgkmcnt(0)" ::: "memory");

                // O^T strip += V^T @ P^T
#pragma unroll
                for (int ks = 0; ks < 2; ks++) {
                    short8 pf = *(const short8*)&Ps[wv][l16 * 64 +
                                 (((ks * 4 + quad) ^ lsw) * 8)];
#pragma unroll
                    for (int i = 0; i < 4; i++) {
                        short8 vf = *(const short8*)&Vt[cur][(i * 16 + l16) * 64 +
                                     (((ks * 4 + quad) ^ lsw) * 8)];
                        ot[i] = __builtin_amdgcn_mfma_f32_16x16x32_bf16(
                            vf, pf, ot[i], 0, 0, 0);
                    }
                }

                if (f + 1 < nk) {
                    writebuf(cur ^ 1);                   // vmcnt wait lands here
                    if (f + 2 < nk) prefetch(half + 2 * (f + 2));
                    HBAR();
                }
            }
        }

        // write partial O (unnormalized) + stats
        if (half == 0) {
            u16* op = Op0 + (size_t)grow * 1024 + hh * 64;
#pragma unroll
            for (int i = 0; i < 4; i++) {
                ushort4 o4;
                o4.x = f2bf(ot[i][0]); o4.y = f2bf(ot[i][1]);
                o4.z = f2bf(ot[i][2]); o4.w = f2bf(ot[i][3]);
                *(ushort4*)&op[i * 16 + quad * 4] = o4;
            }
        } else {
            u16* op = Op1qkv + (size_t)grow * QKVLD + 2048 + hh * 64;
#pragma unroll
            for (int i = 0; i < 4; i++) {
                ushort4 o4;
                o4.x = f2bf(ot[i][0]); o4.y = f2bf(ot[i][1]);
                o4.z = f2bf(ot[i][2]); o4.w = f2bf(ot[i][3]);
                *(ushort4*)&op[i * 16 + quad * 4] = o4;
            }
        }
        if (quad == 0) {
            stats[((size_t)(half * 2 + 0) * 4096 + grow) * 16 + hh] = m2;
            stats[((size_t)(half * 2 + 1) * 4096 + grow) * 16 + hh] = lrow;
        }
    }
}

// ---------------- Flash merge: O = (w0 Oa + w1 Ob) / (w0 l0 + w1 l1) ---------
__global__ __launch_bounds__(256)
void flash_merge(u16* __restrict__ QKV, const u16* __restrict__ Op0,
                 const float* __restrict__ stats) {
    const int row = blockIdx.x;               // 0..4095
    const int tid = threadIdx.x;
    const int col = tid * 4;
    const int hh = col >> 6;
    const float m0 = stats[((size_t)0 * 4096 + row) * 16 + hh];
    const float l0 = stats[((size_t)1 * 4096 + row) * 16 + hh];
    const float m1 = stats[((size_t)2 * 4096 + row) * 16 + hh];
    const float l1 = stats[((size_t)3 * 4096 + row) * 16 + hh];
    const float m  = fmaxf(m0, m1);
    const float w0 = exp2f(m0 - m), w1 = exp2f(m1 - m);
    const float inv = 1.0f / (w0 * l0 + w1 * l1);
    ushort4 a = *(const ushort4*)&Op0[(size_t)row * 1024 + col];
    ushort4 b = *(const ushort4*)&QKV[(size_t)row * QKVLD + 2048 + col];
    ushort4 o;
    o.x = f2bf((w0 * bf2f(a.x) + w1 * bf2f(b.x)) * inv);
    o.y = f2bf((w0 * bf2f(a.y) + w1 * bf2f(b.y)) * inv);
    o.z = f2bf((w0 * bf2f(a.z) + w1 * bf2f(b.z)) * inv);
    o.w = f2bf((w0 * bf2f(a.w) + w1 * bf2f(b.w)) * inv);
    *(ushort4*)&QKV[(size_t)row * QKVLD + col] = o;
}

// ---------------- Launcher ---------------------------------------------------
// Inputs fp32, output fp32 [B,T,E].
extern "C" void kernel_launch(void* const* d_in, const int* in_sizes, int n_in,
                              void* d_out, int out_size, void* d_ws, size_t ws_size,
                              hipStream_t stream) {
    const float* x   = (const float*)d_in[0];
    const float* Wq  = (const float*)d_in[1];
    const float* Wk  = (const float*)d_in[2];
    const float* Wv  = (const float*)d_in[3];
    const float* Wo  = (const float*)d_in[4];
    const float* bo  = (const float*)d_in[5];
    const float* W1  = (const float*)d_in[6];
    const float* b1  = (const float*)d_in[7];
    const float* W2  = (const float*)d_in[8];
    const float* b2  = (const float*)d_in[9];
    const float* g1  = (const float*)d_in[10];
    const float* be1 = (const float*)d_in[11];
    const float* g2  = (const float*)d_in[12];
    const float* be2 = (const float*)d_in[13];

    // Workspace (40 MB):
    //   [ 0,24M): QKV bf16 [4096][3072]; Op1 overwrites V-cols after vcopy;
    //             after O-proj: F1 [0,16M), W2T [16,24M)
    //   [24,32M): Op0 bf16 [4096][1024]; later X1 bf16 (same slot)
    //   [32,40M): Vg bf16 [32][64][2048] (V pre-transposed per (b,h))
    // d_out (16 MB fp32): [0,8M) h bf16; [8,16M): WqkvT(6M)+WoT(2M) early;
    //   stats (1M, over dead WqkvT) during flash; W1T (8M) late.
    char* wsb = (char*)d_ws;
    u16*   QKV = (u16*)wsb;
    u16*   F1  = (u16*)wsb;                              // [4096][2048]
    u16*   W2T = (u16*)(wsb + 16u * 1024 * 1024);        // [1024][4096]
    u16*   Op0 = (u16*)(wsb + 24u * 1024 * 1024);        // [4096][1024]
    u16*   X1b = Op0;                                    // X1 bf16, same slot
    u16*   Vg  = (u16*)(wsb + 32u * 1024 * 1024);        // [32][64][2048]
    u16*   h     = (u16*)d_out;
    u16*   WT    = (u16*)((char*)d_out + 8u * 1024 * 1024);
    u16*   WqkvT = WT;                                   // [3072][1024] (early)
    u16*   WoT   = WT + 3u * 1024 * 1024;                // [1024][1024]
    float* stats = (float*)WT;                           // 1 MB (over dead WqkvT)
    u16*   W1T   = WT;                                   // [4096][1024] (late)

    // 0. early weight transposes (fp32 -> bf16, B^T layout)
    transpose_w4<<<dim3(16, 16, 4), 256, 0, stream>>>(
        Wq, Wk, Wv, Wo,
        WqkvT, WqkvT + 1024u * 1024, WqkvT + 2048u * 1024, WoT);

    // 1. h = LN(x, g1, be1)
    ln_kernel<float><<<Mn, 256, 0, stream>>>(x, g1, be1, h);

    // 2. QKV = h @ [Wq|Wk|Wv]; Q columns pre-scaled by QSC
    gemm_bt<128, 0, 0, 0, 0, 1><<<dim3(24, 32), 256, 0, stream>>>(
        h, En, WqkvT, En, nullptr, nullptr, QKV, QKVLD, En);

    // 3. Vg = V^T per (b,h)   (V-cols of QKV then reusable as Op1)
    vcopy_t<<<dim3(1, 32, 32), 256, 0, stream>>>(QKV, Vg);

    // 4. split-K flash pass 1 -> partials + stats  (1024 blocks, 4/CU)
    flash_pass1<<<dim3(32, Hn, Bn), 256, 0, stream>>>(QKV, Vg, Op0, QKV, stats);

    // 5. merge partials -> O into QKV cols [0,1024)
    flash_merge<<<Mn, 256, 0, stream>>>(QKV, Op0, stats);

    // 6. X1 = x + O @ Wo + bo   (bf16 out, overwrites Op0)
    gemm_bt<64, 1, 0, 1, 0, 0><<<dim3(8, 64), 256, 0, stream>>>(
        QKV, QKVLD, WoT, En, bo, x, X1b, En, En);

    // 7. late weight transposes (QKV + WT regions now dead)
    transpose_w<<<dim3(64, 16), 256, 0, stream>>>(W1, W1T, 1024, 4096);
    transpose_w<<<dim3(16, 64), 256, 0, stream>>>(W2, W2T, 4096, 1024);

    // 8. h2 = LN(X1, g2, be2)
    ln_kernel<u16><<<Mn, 256, 0, stream>>>(X1b, g2, be2, h);

    // 9. FFN in 2 halves of 2048; X1b accumulates in place; final -> d_out fp32
    gemm_bt<128, 1, 1, 0, 0, 0><<<dim3(16, 32), 256, 0, stream>>>(
        h, En, W1T, En, b1, nullptr, F1, 2048, En);
    gemm_bt<64, 0, 0, 2, 0, 0><<<dim3(8, 64), 256, 0, stream>>>(
        F1, 2048, W2T, DFFn, nullptr, X1b, X1b, En, 2048);
    gemm_bt<128, 1, 1, 0, 0, 0><<<dim3(16, 32), 256, 0, stream>>>(
        h, En, W1T + 2048u * 1024, En, b1 + 2048, nullptr, F1, 2048, En);
    gemm_bt<64, 1, 0, 2, 1, 0><<<dim3(8, 64), 256, 0, stream>>>(
        F1, 2048, W2T + 2048, DFFn, b2, X1b, (float*)d_out, En, 2048);
}

// Round 12
// 386.120 us; speedup vs baseline: 1.0355x; 1.0155x over previous
//
#include <hip/hip_runtime.h>
#include <hip/hip_bf16.h>
#include <math.h>

// Problem constants
#define Bn 2
#define Tn 2048
#define En 1024
#define Hn 16
#define DFFn 4096
#define Mn (Bn*Tn)   // 4096 rows
#define QKVLD 3072   // fused QKV leading dim

typedef __hip_bfloat16 bf16;
typedef unsigned short u16;
typedef unsigned int u32;
typedef __attribute__((ext_vector_type(8))) short short8;
typedef __attribute__((ext_vector_type(4))) float f32x4;

typedef __attribute__((address_space(1))) const void cg_void;
typedef __attribute__((address_space(3))) void lds_void;

// Q pre-scale folded into QKV GEMM: E^-0.5 * log2(e)
#define QSC 0.0450842200278f

// lgkm-only barrier: LDS writes visible + wave sync; vmcnt (global loads in
// flight to wave-private registers) NOT drained -- prefetches survive it.
#define HBAR() asm volatile("s_waitcnt lgkmcnt(0)\n\ts_barrier" ::: "memory")

__device__ __forceinline__ u16 f2bf(float f) {
    bf16 h = __float2bfloat16(f);
    u16 u; __builtin_memcpy(&u, &h, 2); return u;
}
__device__ __forceinline__ float bf2f(u16 u) {
    u32 x = ((u32)u) << 16; float f; __builtin_memcpy(&f, &x, 4); return f;
}

// ---------------- 4x weight transpose+convert (1024x1024 each) ---------------
__global__ __launch_bounds__(256)
void transpose_w4(const float* __restrict__ s0, const float* __restrict__ s1,
                  const float* __restrict__ s2, const float* __restrict__ s3,
                  u16* __restrict__ d0, u16* __restrict__ d1,
                  u16* __restrict__ d2, u16* __restrict__ d3) {
    const float* src = (blockIdx.z == 0) ? s0 : (blockIdx.z == 1) ? s1
                     : (blockIdx.z == 2) ? s2 : s3;
    u16* dst = (blockIdx.z == 0) ? d0 : (blockIdx.z == 1) ? d1
             : (blockIdx.z == 2) ? d2 : d3;
    __shared__ float t[64][65];
    const int r0 = blockIdx.y * 64, c0 = blockIdx.x * 64;
    const int tr = threadIdx.x >> 6, tc = threadIdx.x & 63;
#pragma unroll
    for (int i = 0; i < 16; i++)
        t[tr + i * 4][tc] = src[(size_t)(r0 + tr + i * 4) * 1024 + c0 + tc];
    __syncthreads();
#pragma unroll
    for (int i = 0; i < 16; i++)
        dst[(size_t)(c0 + tr + i * 4) * 1024 + r0 + tc] = f2bf(t[tc][tr + i * 4]);
}

// ---------------- generic weight transpose: src fp32 [R][C] -> bf16 [C][R] ---
__global__ __launch_bounds__(256)
void transpose_w(const float* __restrict__ src, u16* __restrict__ dst,
                 int R, int C) {
    __shared__ float t[64][65];
    const int r0 = blockIdx.y * 64, c0 = blockIdx.x * 64;
    const int tr = threadIdx.x >> 6, tc = threadIdx.x & 63;
#pragma unroll
    for (int i = 0; i < 16; i++)
        t[tr + i * 4][tc] = src[(size_t)(r0 + tr + i * 4) * C + c0 + tc];
    __syncthreads();
#pragma unroll
    for (int i = 0; i < 16; i++)
        dst[(size_t)(c0 + tr + i * 4) * R + r0 + tc] = f2bf(t[tc][tr + i * 4]);
}

// ---------------- V copy-transpose: QKV V-cols -> Vg[bh][dh=64][tok=2048] ----
__global__ __launch_bounds__(256)
void vcopy_t(const u16* __restrict__ QKV, u16* __restrict__ Vg) {
    const int bh = blockIdx.z;          // bb*16+hh
    const int t0 = blockIdx.y * 64;     // token tile
    __shared__ u16 t[64][65];
    const int tr = threadIdx.x >> 6, tc = threadIdx.x & 63;
    const u16* src = QKV + (size_t)(bh >> 4) * 2048 * QKVLD + 2048 + (bh & 15) * 64;
#pragma unroll
    for (int i = 0; i < 16; i++)
        t[tr + i * 4][tc] = src[(size_t)(t0 + tr + i * 4) * QKVLD + tc];  // [tokl][dh]
    __syncthreads();
    u16* dst = Vg + (size_t)bh * 64 * 2048;
#pragma unroll
    for (int i = 0; i < 16; i++)
        dst[(size_t)(tr + i * 4) * 2048 + t0 + tc] = t[tc][tr + i * 4];
}

// ---------------- LayerNorm: one block per row of E=1024 ---------------------
template<typename AT>
__global__ __launch_bounds__(256)
void ln_kernel(const AT* __restrict__ x, const float* __restrict__ g,
               const float* __restrict__ b, u16* __restrict__ out) {
    const int row = blockIdx.x;
    const int tid = threadIdx.x;
    const AT* xp = x + (size_t)row * En;
    float v[4];
    float s = 0.f, sq = 0.f;
#pragma unroll
    for (int i = 0; i < 4; i++) {
        if constexpr (sizeof(AT) == 2) v[i] = bf2f(xp[tid + i * 256]);
        else                           v[i] = (float)xp[tid + i * 256];
        s += v[i];
        sq += v[i] * v[i];
    }
    __shared__ float rs[256], rq[256];
    rs[tid] = s; rq[tid] = sq;
    __syncthreads();
    for (int st = 128; st > 0; st >>= 1) {
        if (tid < st) { rs[tid] += rs[tid + st]; rq[tid] += rq[tid + st]; }
        __syncthreads();
    }
    const float mu  = rs[0] * (1.0f / En);
    const float var = rq[0] * (1.0f / En) - mu * mu;
    const float inv = rsqrtf(var + 1e-5f);
#pragma unroll
    for (int i = 0; i < 4; i++) {
        const int c = tid + i * 256;
        out[(size_t)row * En + c] = f2bf((v[i] - mu) * inv * g[c] + b[c]);
    }
}

// ---------------- m97-style GEMM + XOR swizzle -------------------------------
// C[4096,N] = A(bf16 [M][K]) @ Wt(bf16 [N][K])^T. TM x 128 tile, BK=32, 4 waves.
// RES: 0 none / 1 fp32 / 2 bf16. SCQ: Q pre-scale for n0<1024.
// SPLITC: N=4096 output split col-wise into Cout/Cout2 (2048 each, ldC both).
// SPLITA: K=4096 input split col-wise into A/A2 (2048 each, ldA both).
template<int TM, int HAS_BIAS, int RELU, int RES, int OUT_F32, int SCQ,
         int SPLITC, int SPLITA>
__global__ __launch_bounds__(256)
void gemm_bt(const u16* __restrict__ A, const u16* __restrict__ A2, int ldA,
             const u16* __restrict__ Wt, int ldW,
             const float* __restrict__ bias, const void* __restrict__ res,
             void* __restrict__ Cout, void* __restrict__ Cout2,
             int ldC, int Kd) {
    constexpr int IF = TM / 32;          // i-frags per wave
    __shared__ __align__(16) u16 As[TM * 32];
    __shared__ __align__(16) u16 Bs[128 * 32];
    const int tid  = threadIdx.x;
    const int lane = tid & 63, wv = tid >> 6;
    const int quad = lane >> 4, l16 = lane & 15;
    const int m0 = blockIdx.y * TM, n0 = blockIdx.x * 128;
    const int rw = (wv >> 1) * (TM / 2), cw = (wv & 1) * 64;
    const int lr  = lane >> 2;                         // row within 16-row chunk
    const int gsw = ((lane & 3) ^ ((lane >> 3) & 3)) * 8;  // swizzled src colgrp
    const int psw = (quad ^ ((l16 >> 1) & 3)) * 8;     // swizzled read colgrp

    f32x4 acc[IF][4] = {};

    for (int kt = 0; kt < Kd; kt += 32) {
        const u16* Ap = (SPLITA && kt >= 2048) ? A2 : A;
        const int  kk = SPLITA ? (kt & 2047) : kt;
        __syncthreads();
#pragma unroll
        for (int t = 0; t < TM / 64; t++) {
            const int row = wv * (TM / 4) + t * 16;
            __builtin_amdgcn_global_load_lds(
                (cg_void*)(const void*)&Ap[(size_t)(m0 + row + lr) * ldA + kk + gsw],
                (lds_void*)(void*)&As[row * 32], 16, 0, 0);
        }
#pragma unroll
        for (int t = 0; t < 2; t++) {
            const int row = wv * 32 + t * 16;
            __builtin_amdgcn_global_load_lds(
                (cg_void*)(const void*)&Wt[(size_t)(n0 + row + lr) * ldW + kt + gsw],
                (lds_void*)(void*)&Bs[row * 32], 16, 0, 0);
        }
        __syncthreads();

        short8 af[IF], bfr[4];
#pragma unroll
        for (int i = 0; i < IF; i++)
            af[i] = *(const short8*)&As[(rw + i * 16 + l16) * 32 + psw];
#pragma unroll
        for (int j = 0; j < 4; j++)
            bfr[j] = *(const short8*)&Bs[(cw + j * 16 + l16) * 32 + psw];
#pragma unroll
        for (int i = 0; i < IF; i++)
#pragma unroll
            for (int j = 0; j < 4; j++)
                acc[i][j] = __builtin_amdgcn_mfma_f32_16x16x32_bf16(
                    af[i], bfr[j], acc[i][j], 0, 0, 0);
    }

    const float qscale = (SCQ && n0 < 1024) ? QSC : 1.0f;
    void* Cp = (SPLITC && n0 >= 2048) ? Cout2 : Cout;
#pragma unroll
    for (int i = 0; i < IF; i++) {
#pragma unroll
        for (int r = 0; r < 4; r++) {
            const int gm = m0 + rw + i * 16 + quad * 4 + r;
#pragma unroll
            for (int j = 0; j < 4; j++) {
                const int gn = n0 + cw + j * 16 + l16;
                const int cn = SPLITC ? (gn & 2047) : gn;
                float c = acc[i][j][r];
                if (HAS_BIAS) c += bias[gn];
                if (RELU) c = fmaxf(c, 0.f);
                if (RES == 1) c += ((const float*)res)[(size_t)gm * ldC + cn];
                if (RES == 2) c += bf2f(((const u16*)res)[(size_t)gm * ldC + cn]);
                if (SCQ) c *= qscale;
                if (OUT_F32) ((float*)Cp)[(size_t)gm * ldC + cn] = c;
                else         ((u16*)Cp)[(size_t)gm * ldC + cn] = f2bf(c);
            }
        }
    }
}

// ---------------- Flash attention pass 1 (split-K) ---------------------------
// Grid (32,16,2): x = pair*2+half. Pair {pr,31-pr}; half h takes kt = h,h+2,...
// Transposed-S, per-lane q stats, double-buffered K/V (register relay, one
// lgkm-only barrier per round). K from QKV [key][dh]; V from Vg [dh][tok].
// XOR-swizzled unpadded stride-64 LDS (40 KB -> 4 blocks/CU).
__global__ __launch_bounds__(256)
void flash_pass1(const u16* __restrict__ QKV, const u16* __restrict__ Vg,
                 u16* __restrict__ Op0, u16* __restrict__ Op1qkv,
                 float* __restrict__ stats) {
    const int pr = blockIdx.x >> 1, half = blockIdx.x & 1;
    const int hh = blockIdx.y, bb = blockIdx.z;
    const int tid  = threadIdx.x;
    const int lane = tid & 63, wv = tid >> 6;
    const int quad = lane >> 4, l16 = lane & 15;

    __shared__ __align__(16) u16 Ks[2][64 * 64];
    __shared__ __align__(16) u16 Vt[2][64 * 64];
    __shared__ __align__(16) u16 Ps[4][16 * 64];

    const size_t rowbase = (size_t)(bb * Tn) * QKVLD;
    const u16* Vgh = Vg + (size_t)(bb * Hn + hh) * 64 * 2048;

    const int sr = tid >> 2;
    const int p0 = (tid & 3) | ((sr & 1) << 2);
    const int p1 = p0 ^ 4;
    const int g0 = p0 ^ (sr & 7), g1 = p1 ^ (sr & 7);
    const int lsw = l16 & 7;                       // fragment-read row swizzle

    uint4 kA, kB, vA, vB;
    auto prefetch = [&](int kt) {
        const size_t kb = rowbase + (size_t)(kt * 64 + sr) * QKVLD + 1024 + hh * 64;
        kA = *(const uint4*)&QKV[kb + g0 * 8];
        kB = *(const uint4*)&QKV[kb + g1 * 8];
        const size_t vb = (size_t)sr * 2048 + kt * 64;
        vA = *(const uint4*)&Vgh[vb + g0 * 8];
        vB = *(const uint4*)&Vgh[vb + g1 * 8];
    };
    auto writebuf = [&](int buf) {
        *(uint4*)&Ks[buf][sr * 64 + p0 * 8] = kA;
        *(uint4*)&Ks[buf][sr * 64 + p1 * 8] = kB;
        *(uint4*)&Vt[buf][sr * 64 + p0 * 8] = vA;
        *(uint4*)&Vt[buf][sr * 64 + p1 * 8] = vB;
    };

    for (int qsel = 0; qsel < 2; qsel++) {
        const int qt = qsel ? (31 - pr) : pr;
        const int nk = (qt >= half) ? ((qt - half) >> 1) + 1 : 0;
        const int qrow = qt * 64 + wv * 16 + l16;
        const int grow = bb * Tn + qrow;

        f32x4 ot[4] = {};
        float m2 = -INFINITY, lrow = 0.f;

        HBAR();
        if (nk > 0) {
            const u16* qp = QKV + rowbase + (size_t)qrow * QKVLD + hh * 64;
            short8 qf[2];
            qf[0] = *(const short8*)&qp[quad * 8];
            qf[1] = *(const short8*)&qp[32 + quad * 8];

            prefetch(half);
            writebuf(0);
            if (nk > 1) prefetch(half + 2);
            HBAR();

            const bool hasdiag = ((qt ^ half) & 1) == 0;
            for (int f = 0; f < nk; f++) {
                const int cur = f & 1;

                f32x4 st[4] = {};
#pragma unroll
                for (int ks = 0; ks < 2; ks++)
#pragma unroll
                    for (int i = 0; i < 4; i++) {
                        short8 kf = *(const short8*)&Ks[cur][(i * 16 + l16) * 64 +
                                     (((ks * 4 + quad) ^ lsw) * 8)];
                        st[i] = __builtin_amdgcn_mfma_f32_16x16x32_bf16(
                            kf, qf[ks], st[i], 0, 0, 0);
                    }

                float tmax = -INFINITY;
                if (hasdiag && f == nk - 1) {
                    const int qloc = wv * 16 + l16;
#pragma unroll
                    for (int i = 0; i < 4; i++)
#pragma unroll
                        for (int r = 0; r < 4; r++) {
                            float s = st[i][r];
                            if (i * 16 + quad * 4 + r > qloc) s = -INFINITY;
                            st[i][r] = s;
                            tmax = fmaxf(tmax, s);
                        }
                } else {
#pragma unroll
                    for (int i = 0; i < 4; i++)
#pragma unroll
                        for (int r = 0; r < 4; r++)
                            tmax = fmaxf(tmax, st[i][r]);
                }
                tmax = fmaxf(tmax, __shfl_xor(tmax, 16));
                tmax = fmaxf(tmax, __shfl_xor(tmax, 32));

                const float mnew = fmaxf(m2, tmax);
                const float alpha = exp2f(m2 - mnew);
                m2 = mnew;
                float psum = 0.f;
#pragma unroll
                for (int i = 0; i < 4; i++)
#pragma unroll
                    for (int r = 0; r < 4; r++) {
                        const float e = exp2f(st[i][r] - mnew);
                        st[i][r] = e;
                        psum += e;
                    }
                psum += __shfl_xor(psum, 16);
                psum += __shfl_xor(psum, 32);
                lrow = lrow * alpha + psum;
#pragma unroll
                for (int i = 0; i < 4; i++) ot[i] *= alpha;

#pragma unroll
                for (int i = 0; i < 4; i++) {
                    uint2 w;
                    w.x = (u32)f2bf(st[i][0]) | ((u32)f2bf(st[i][1]) << 16);
                    w.y = (u32)f2bf(st[i][2]) | ((u32)f2bf(st[i][3]) << 16);
                    const int g = (i * 2 + (quad >> 1)) ^ lsw;
                    *(uint2*)&Ps[wv][l16 * 64 + g * 8 + (quad & 1) * 4] = w;
                }
                asm volatile("s_waitcnt lgkmcnt(0)" ::: "memory");

#pragma unroll
                for (int ks = 0; ks < 2; ks++) {
                    short8 pf = *(const short8*)&Ps[wv][l16 * 64 +
                                 (((ks * 4 + quad) ^ lsw) * 8)];
#pragma unroll
                    for (int i = 0; i < 4; i++) {
                        short8 vf = *(const short8*)&Vt[cur][(i * 16 + l16) * 64 +
                                     (((ks * 4 + quad) ^ lsw) * 8)];
                        ot[i] = __builtin_amdgcn_mfma_f32_16x16x32_bf16(
                            vf, pf, ot[i], 0, 0, 0);
                    }
                }

                if (f + 1 < nk) {
                    writebuf(cur ^ 1);
                    if (f + 2 < nk) prefetch(half + 2 * (f + 2));
                    HBAR();
                }
            }
        }

        u16* op = (half == 0) ? (Op0 + (size_t)grow * 1024 + hh * 64)
                              : (Op1qkv + (size_t)grow * QKVLD + 2048 + hh * 64);
#pragma unroll
        for (int i = 0; i < 4; i++) {
            ushort4 o4;
            o4.x = f2bf(ot[i][0]); o4.y = f2bf(ot[i][1]);
            o4.z = f2bf(ot[i][2]); o4.w = f2bf(ot[i][3]);
            *(ushort4*)&op[i * 16 + quad * 4] = o4;
        }
        if (quad == 0) {
            stats[((size_t)(half * 2 + 0) * 4096 + grow) * 16 + hh] = m2;
            stats[((size_t)(half * 2 + 1) * 4096 + grow) * 16 + hh] = lrow;
        }
    }
}

// ---------------- Flash merge: O = (w0 Oa + w1 Ob) / (w0 l0 + w1 l1) ---------
__global__ __launch_bounds__(256)
void flash_merge(u16* __restrict__ QKV, const u16* __restrict__ Op0,
                 const float* __restrict__ stats) {
    const int row = blockIdx.x;
    const int tid = threadIdx.x;
    const int col = tid * 4;
    const int hh = col >> 6;
    const float m0 = stats[((size_t)0 * 4096 + row) * 16 + hh];
    const float l0 = stats[((size_t)1 * 4096 + row) * 16 + hh];
    const float m1 = stats[((size_t)2 * 4096 + row) * 16 + hh];
    const float l1 = stats[((size_t)3 * 4096 + row) * 16 + hh];
    const float m  = fmaxf(m0, m1);
    const float w0 = exp2f(m0 - m), w1 = exp2f(m1 - m);
    const float inv = 1.0f / (w0 * l0 + w1 * l1);
    ushort4 a = *(const ushort4*)&Op0[(size_t)row * 1024 + col];
    ushort4 b = *(const ushort4*)&QKV[(size_t)row * QKVLD + 2048 + col];
    ushort4 o;
    o.x = f2bf((w0 * bf2f(a.x) + w1 * bf2f(b.x)) * inv);
    o.y = f2bf((w0 * bf2f(a.y) + w1 * bf2f(b.y)) * inv);
    o.z = f2bf((w0 * bf2f(a.z) + w1 * bf2f(b.z)) * inv);
    o.w = f2bf((w0 * bf2f(a.w) + w1 * bf2f(b.w)) * inv);
    *(ushort4*)&QKV[(size_t)row * QKVLD + col] = o;
}

// ---------------- Launcher ---------------------------------------------------
// Inputs fp32, output fp32 [B,T,E].
extern "C" void kernel_launch(void* const* d_in, const int* in_sizes, int n_in,
                              void* d_out, int out_size, void* d_ws, size_t ws_size,
                              hipStream_t stream) {
    const float* x   = (const float*)d_in[0];
    const float* Wq  = (const float*)d_in[1];
    const float* Wk  = (const float*)d_in[2];
    const float* Wv  = (const float*)d_in[3];
    const float* Wo  = (const float*)d_in[4];
    const float* bo  = (const float*)d_in[5];
    const float* W1  = (const float*)d_in[6];
    const float* b1  = (const float*)d_in[7];
    const float* W2  = (const float*)d_in[8];
    const float* b2  = (const float*)d_in[9];
    const float* g1  = (const float*)d_in[10];
    const float* be1 = (const float*)d_in[11];
    const float* g2  = (const float*)d_in[12];
    const float* be2 = (const float*)d_in[13];

    // Workspace (40 MB):
    //   [ 0,24M): QKV bf16 [4096][3072]; after O-proj: F1a [0,16M) [4096][2048]
    //   [16,24M): W2T bf16 [1024][4096] (written after O-proj)
    //   [24,32M): Op0 bf16 [4096][1024]; later X1 bf16 (same slot)
    //   [32,40M): Vg [32][64][2048] (V^T per (b,h)); after flash: F1b [4096][2048]
    // d_out (16 MB fp32): [0,8M) h bf16; [8,16M): WqkvT(6M)+WoT(2M) early;
    //   stats (1M over dead WqkvT) during flash; W1T (8M) late.
    char* wsb = (char*)d_ws;
    u16*   QKV = (u16*)wsb;
    u16*   F1a = (u16*)wsb;                              // [4096][2048]
    u16*   W2T = (u16*)(wsb + 16u * 1024 * 1024);        // [1024][4096]
    u16*   Op0 = (u16*)(wsb + 24u * 1024 * 1024);        // [4096][1024]
    u16*   X1b = Op0;                                    // X1 bf16, same slot
    u16*   Vg  = (u16*)(wsb + 32u * 1024 * 1024);        // [32][64][2048]
    u16*   F1b = Vg;                                     // [4096][2048]
    u16*   h     = (u16*)d_out;
    u16*   WT    = (u16*)((char*)d_out + 8u * 1024 * 1024);
    u16*   WqkvT = WT;                                   // [3072][1024] (early)
    u16*   WoT   = WT + 3u * 1024 * 1024;                // [1024][1024]
    float* stats = (float*)WT;                           // 1 MB (over dead WqkvT)
    u16*   W1T   = WT;                                   // [4096][1024] (late)

    // 0. early weight transposes (fp32 -> bf16, B^T layout)
    transpose_w4<<<dim3(16, 16, 4), 256, 0, stream>>>(
        Wq, Wk, Wv, Wo,
        WqkvT, WqkvT + 1024u * 1024, WqkvT + 2048u * 1024, WoT);

    // 1. h = LN(x, g1, be1)
    ln_kernel<float><<<Mn, 256, 0, stream>>>(x, g1, be1, h);

    // 2. QKV = h @ [Wq|Wk|Wv]; Q columns pre-scaled by QSC
    gemm_bt<128, 0, 0, 0, 0, 1, 0, 0><<<dim3(24, 32), 256, 0, stream>>>(
        h, nullptr, En, WqkvT, En, nullptr, nullptr, QKV, nullptr, QKVLD, En);

    // 3. Vg = V^T per (b,h)
    vcopy_t<<<dim3(1, 32, 32), 256, 0, stream>>>(QKV, Vg);

    // 4. split-K flash pass 1 -> partials + stats  (1024 blocks, 4/CU)
    flash_pass1<<<dim3(32, Hn, Bn), 256, 0, stream>>>(QKV, Vg, Op0, QKV, stats);

    // 5. merge partials -> O into QKV cols [0,1024)
    flash_merge<<<Mn, 256, 0, stream>>>(QKV, Op0, stats);

    // 6. X1 = x + O @ Wo + bo   (bf16 out, overwrites Op0)
    gemm_bt<64, 1, 0, 1, 0, 0, 0, 0><<<dim3(8, 64), 256, 0, stream>>>(
        QKV, nullptr, QKVLD, WoT, En, bo, x, X1b, nullptr, En, En);

    // 7. late weight transposes (QKV + WT + Vg regions now dead)
    transpose_w<<<dim3(64, 16), 256, 0, stream>>>(W1, W1T, 1024, 4096);
    transpose_w<<<dim3(16, 64), 256, 0, stream>>>(W2, W2T, 4096, 1024);

    // 8. h2 = LN(X1, g2, be2)
    ln_kernel<u16><<<Mn, 256, 0, stream>>>(X1b, g2, be2, h);

    // 9. FF1 fused: relu(h2 @ W1 + b1) -> F1a (cols<2048) / F1b (cols>=2048)
    //    N=4096, 1024 blocks = 4/CU
    gemm_bt<128, 1, 1, 0, 0, 0, 1, 0><<<dim3(32, 32), 256, 0, stream>>>(
        h, nullptr, En, W1T, En, b1, nullptr, F1a, F1b, 2048, En);

    // 10. FF2 fused: out = X1 + [F1a|F1b] @ W2 + b2 -> d_out fp32, K=4096
    gemm_bt<64, 1, 0, 2, 1, 0, 0, 1><<<dim3(8, 64), 256, 0, stream>>>(
        F1a, F1b, 2048, W2T, DFFn, b2, X1b, (float*)d_out, nullptr, En, DFFn);
}